// Round 2
// baseline (568.670 us; speedup 1.0000x reference)
//
#include <hip/hip_runtime.h>
#include <cstdint>
#include <cstddef>

// Problem constants (fixed by setup_inputs; harness always uses this shape).
constexpr int Bc = 4;
constexpr int Hc = 376;
constexpr int Wc = 1241;
constexpr int Cc = 64;
constexpr int HW = Hc * Wc;          // 466616  (divisible by 4)
constexpr int NUM_PIX = Bc * HW;     // 1866464

// ws layout: [0, NUM_PIX*8)  u64 packed (depth_bits<<32 | idx) entries

__global__ void init_entries(uint4* __restrict__ p, int n16) {
    int t = blockIdx.x * blockDim.x + threadIdx.x;
    if (t < n16) p[t] = make_uint4(0xFFFFFFFFu, 0xFFFFFFFFu, 0xFFFFFFFFu, 0xFFFFFFFFu);
}

__global__ void scatter_points(const int* __restrict__ coords,
                               const float* __restrict__ Km,
                               unsigned long long* __restrict__ entries,
                               int N) {
    int n = blockIdx.x * blockDim.x + threadIdx.x;
    if (n >= N) return;

    const int4 co = *(const int4*)(coords + 4 * (size_t)n);  // (b, z, y, x)
    const int   bi = co.x;
    const float zf = (float)co.y;
    const float yf = (float)co.z;
    const float xf = (float)co.w;

    // K @ R with R=[[0,-1,0],[0,0,-1],[1,0,0]] -> KR[i] = [K[i][2], -K[i][0], -K[i][1]] (exact)
    // P = KR @ V2P, V2P rows: [0.75,0,0,0.375],[0,0.75,0,-24.625],[0,0,0.75,-24.625]
    // Replicate BLAS fp32 FMA ascending-k accumulation.
    float P0[4], P1[4], P2[4];
    {
        const float xo = 0.375f, yo = -24.625f, zo = -24.625f;
        float KR0, KR1, KR2;
        // row 0
        KR0 = Km[2]; KR1 = -Km[0]; KR2 = -Km[1];
        P0[0] = __fmaf_rn(KR0, 0.75f, 0.0f);
        P0[1] = __fmaf_rn(KR1, 0.75f, 0.0f);
        P0[2] = __fmaf_rn(KR2, 0.75f, 0.0f);
        P0[3] = __fmaf_rn(KR2, zo, __fmaf_rn(KR1, yo, __fmaf_rn(KR0, xo, 0.0f)));
        // row 1
        KR0 = Km[5]; KR1 = -Km[3]; KR2 = -Km[4];
        P1[0] = __fmaf_rn(KR0, 0.75f, 0.0f);
        P1[1] = __fmaf_rn(KR1, 0.75f, 0.0f);
        P1[2] = __fmaf_rn(KR2, 0.75f, 0.0f);
        P1[3] = __fmaf_rn(KR2, zo, __fmaf_rn(KR1, yo, __fmaf_rn(KR0, xo, 0.0f)));
        // row 2
        KR0 = Km[8]; KR1 = -Km[6]; KR2 = -Km[7];
        P2[0] = __fmaf_rn(KR0, 0.75f, 0.0f);
        P2[1] = __fmaf_rn(KR1, 0.75f, 0.0f);
        P2[2] = __fmaf_rn(KR2, 0.75f, 0.0f);
        P2[3] = __fmaf_rn(KR2, zo, __fmaf_rn(KR1, yo, __fmaf_rn(KR0, xo, 0.0f)));
    }

    // p = xyz1 @ P.T, ascending-k FMA chain: (((x*Pi0) fma y*Pi1) fma z*Pi2) fma 1*Pi3
    float p0 = __fmaf_rn(1.0f, P0[3], __fmaf_rn(zf, P0[2], __fmaf_rn(yf, P0[1], __fmaf_rn(xf, P0[0], 0.0f))));
    float p1 = __fmaf_rn(1.0f, P1[3], __fmaf_rn(zf, P1[2], __fmaf_rn(yf, P1[1], __fmaf_rn(xf, P1[0], 0.0f))));
    float depth = __fmaf_rn(1.0f, P2[3], __fmaf_rn(zf, P2[2], __fmaf_rn(yf, P2[1], __fmaf_rn(xf, P2[0], 0.0f))));

    const bool dok = depth > 1e-6f;
    const float safe_d = dok ? depth : 1.0f;
    const int u = (int)floorf(__fdiv_rn(p0, safe_d));
    const int v = (int)floorf(__fdiv_rn(p1, safe_d));

    if (dok && u >= 0 && u < Wc && v >= 0 && v < Hc && bi >= 0 && bi < Bc) {
        const int pix = bi * HW + v * Wc + u;
        const unsigned long long key =
            ((unsigned long long)__float_as_uint(depth) << 32) | (unsigned int)n;
        atomicMin(&entries[pix], key);
    }
}

// Fused decode + gather: one thread per pixel-quad (4 consecutive pixels of one
// image). Reads the 4 packed u64 entries ONCE, decodes winner idx + inv_depth in
// registers, writes inv_depth (float4), then loops all 16 channel-groups doing
// 4x float4 feature gathers -> register transpose -> 4x coalesced float4 plane
// stores. Eliminates the decode kernel and the widx intermediate entirely.
__global__ void decode_gather(const unsigned long long* __restrict__ entries,
                              const float* __restrict__ feat,
                              float* __restrict__ out_feat,
                              float* __restrict__ out_inv) {
    const int q = blockIdx.x * blockDim.x + threadIdx.x;  // pixel-quad within one image
    if (q >= HW / 4) return;
    const int b = blockIdx.y;
    const int local = q * 4;
    const size_t pixbase = (size_t)b * HW + local;

    const unsigned long long e0 = entries[pixbase + 0];
    const unsigned long long e1 = entries[pixbase + 1];
    const unsigned long long e2 = entries[pixbase + 2];
    const unsigned long long e3 = entries[pixbase + 3];

    int   i0 = -1, i1 = -1, i2 = -1, i3 = -1;
    float v0 = 0.0f, v1 = 0.0f, v2 = 0.0f, v3 = 0.0f;
    if (e0 != ~0ULL) { i0 = (int)(unsigned int)(e0 & 0xFFFFFFFFu); v0 = __fdiv_rn(1.0f, __uint_as_float((unsigned int)(e0 >> 32))); }
    if (e1 != ~0ULL) { i1 = (int)(unsigned int)(e1 & 0xFFFFFFFFu); v1 = __fdiv_rn(1.0f, __uint_as_float((unsigned int)(e1 >> 32))); }
    if (e2 != ~0ULL) { i2 = (int)(unsigned int)(e2 & 0xFFFFFFFFu); v2 = __fdiv_rn(1.0f, __uint_as_float((unsigned int)(e2 >> 32))); }
    if (e3 != ~0ULL) { i3 = (int)(unsigned int)(e3 & 0xFFFFFFFFu); v3 = __fdiv_rn(1.0f, __uint_as_float((unsigned int)(e3 >> 32))); }

    *(float4*)(out_inv + pixbase) = make_float4(v0, v1, v2, v3);

    float* ob = out_feat + ((size_t)b * Cc) * HW + local;
    const float4 z4 = make_float4(0.0f, 0.0f, 0.0f, 0.0f);

#pragma unroll
    for (int cg = 0; cg < 16; ++cg) {
        const int c0 = cg * 4;
        const float4 r0 = (i0 < 0) ? z4 : *(const float4*)(feat + (size_t)i0 * Cc + c0);
        const float4 r1 = (i1 < 0) ? z4 : *(const float4*)(feat + (size_t)i1 * Cc + c0);
        const float4 r2 = (i2 < 0) ? z4 : *(const float4*)(feat + (size_t)i2 * Cc + c0);
        const float4 r3 = (i3 < 0) ? z4 : *(const float4*)(feat + (size_t)i3 * Cc + c0);

        float* p = ob + (size_t)c0 * HW;
        *(float4*)(p)                = make_float4(r0.x, r1.x, r2.x, r3.x);
        *(float4*)(p + HW)           = make_float4(r0.y, r1.y, r2.y, r3.y);
        *(float4*)(p + 2 * (size_t)HW) = make_float4(r0.z, r1.z, r2.z, r3.z);
        *(float4*)(p + 3 * (size_t)HW) = make_float4(r0.w, r1.w, r2.w, r3.w);
    }
}

extern "C" void kernel_launch(void* const* d_in, const int* in_sizes, int n_in,
                              void* d_out, int out_size, void* d_ws, size_t ws_size,
                              hipStream_t stream) {
    const float* features = (const float*)d_in[0];
    const int*   coords   = (const int*)d_in[1];
    const float* Km       = (const float*)d_in[2];
    const int N = in_sizes[1] / 4;  // 200000

    unsigned long long* entries = (unsigned long long*)d_ws;

    float* out_feat = (float*)d_out;                          // B*C*H*W
    float* out_inv  = (float*)d_out + (size_t)Bc * Cc * HW;   // B*H*W

    const int n16 = NUM_PIX / 2;  // uint4 count for the u64 buffer
    init_entries<<<(n16 + 255) / 256, 256, 0, stream>>>((uint4*)entries, n16);

    scatter_points<<<(N + 255) / 256, 256, 0, stream>>>(coords, Km, entries, N);

    dim3 ggrid((HW / 4 + 255) / 256, Bc);
    decode_gather<<<ggrid, 256, 0, stream>>>(entries, features, out_feat, out_inv);
}

// Round 3
// 527.870 us; speedup vs baseline: 1.0773x; 1.0773x over previous
//
#include <hip/hip_runtime.h>
#include <cstdint>
#include <cstddef>

// Problem constants (fixed by setup_inputs; harness always uses this shape).
constexpr int Bc = 4;
constexpr int Hc = 376;
constexpr int Wc = 1241;
constexpr int Cc = 64;
constexpr int HW = Hc * Wc;          // 466616  (divisible by 4)
constexpr int NUM_PIX = Bc * HW;     // 1866464

// ws layout: [0, NUM_PIX*8)            u64 packed (depth_bits<<32 | idx) entries
//            [NUM_PIX*8, NUM_PIX*12)   int32 win_idx  (16B-aligned)

__global__ void scatter_points(const int* __restrict__ coords,
                               const float* __restrict__ Km,
                               unsigned long long* __restrict__ entries,
                               int N) {
    int n = blockIdx.x * blockDim.x + threadIdx.x;
    if (n >= N) return;

    const int4 co = *(const int4*)(coords + 4 * (size_t)n);  // (b, z, y, x)
    const int   bi = co.x;
    const float zf = (float)co.y;
    const float yf = (float)co.z;
    const float xf = (float)co.w;

    // K @ R with R=[[0,-1,0],[0,0,-1],[1,0,0]] -> KR[i] = [K[i][2], -K[i][0], -K[i][1]] (exact)
    // P = KR @ V2P, V2P rows: [0.75,0,0,0.375],[0,0.75,0,-24.625],[0,0,0.75,-24.625]
    // Replicate BLAS fp32 FMA ascending-k accumulation.
    float P0[4], P1[4], P2[4];
    {
        const float xo = 0.375f, yo = -24.625f, zo = -24.625f;
        float KR0, KR1, KR2;
        // row 0
        KR0 = Km[2]; KR1 = -Km[0]; KR2 = -Km[1];
        P0[0] = __fmaf_rn(KR0, 0.75f, 0.0f);
        P0[1] = __fmaf_rn(KR1, 0.75f, 0.0f);
        P0[2] = __fmaf_rn(KR2, 0.75f, 0.0f);
        P0[3] = __fmaf_rn(KR2, zo, __fmaf_rn(KR1, yo, __fmaf_rn(KR0, xo, 0.0f)));
        // row 1
        KR0 = Km[5]; KR1 = -Km[3]; KR2 = -Km[4];
        P1[0] = __fmaf_rn(KR0, 0.75f, 0.0f);
        P1[1] = __fmaf_rn(KR1, 0.75f, 0.0f);
        P1[2] = __fmaf_rn(KR2, 0.75f, 0.0f);
        P1[3] = __fmaf_rn(KR2, zo, __fmaf_rn(KR1, yo, __fmaf_rn(KR0, xo, 0.0f)));
        // row 2
        KR0 = Km[8]; KR1 = -Km[6]; KR2 = -Km[7];
        P2[0] = __fmaf_rn(KR0, 0.75f, 0.0f);
        P2[1] = __fmaf_rn(KR1, 0.75f, 0.0f);
        P2[2] = __fmaf_rn(KR2, 0.75f, 0.0f);
        P2[3] = __fmaf_rn(KR2, zo, __fmaf_rn(KR1, yo, __fmaf_rn(KR0, xo, 0.0f)));
    }

    // p = xyz1 @ P.T, ascending-k FMA chain: (((x*Pi0) fma y*Pi1) fma z*Pi2) fma 1*Pi3
    float p0 = __fmaf_rn(1.0f, P0[3], __fmaf_rn(zf, P0[2], __fmaf_rn(yf, P0[1], __fmaf_rn(xf, P0[0], 0.0f))));
    float p1 = __fmaf_rn(1.0f, P1[3], __fmaf_rn(zf, P1[2], __fmaf_rn(yf, P1[1], __fmaf_rn(xf, P1[0], 0.0f))));
    float depth = __fmaf_rn(1.0f, P2[3], __fmaf_rn(zf, P2[2], __fmaf_rn(yf, P2[1], __fmaf_rn(xf, P2[0], 0.0f))));

    const bool dok = depth > 1e-6f;
    const float safe_d = dok ? depth : 1.0f;
    const int u = (int)floorf(__fdiv_rn(p0, safe_d));
    const int v = (int)floorf(__fdiv_rn(p1, safe_d));

    if (dok && u >= 0 && u < Wc && v >= 0 && v < Hc && bi >= 0 && bi < Bc) {
        const int pix = bi * HW + v * Wc + u;
        const unsigned long long key =
            ((unsigned long long)__float_as_uint(depth) << 32) | (unsigned int)n;
        atomicMin(&entries[pix], key);
    }
}

__global__ void decode_entries(const unsigned long long* __restrict__ entries,
                               int* __restrict__ widx,
                               float* __restrict__ inv_depth) {
    int t = blockIdx.x * blockDim.x + threadIdx.x;
    if (t >= NUM_PIX) return;
    const unsigned long long e = entries[t];
    int idx = -1;
    float inv = 0.0f;
    if (e != ~0ULL) {
        idx = (int)(unsigned int)(e & 0xFFFFFFFFu);
        const float dep = __uint_as_float((unsigned int)(e >> 32));
        inv = __fdiv_rn(1.0f, dep);
    }
    widx[t] = idx;
    inv_depth[t] = inv;
}

// One thread per (pixel-quad, channel, image). High-TLP latency-tolerant gather;
// round-1 showed instruction count is NOT the limiter here (4x cut was neutral),
// so keep the measured-best scalar-channel form.
__global__ void gather_features(const int* __restrict__ widx,
                                const float* __restrict__ feat,
                                float* __restrict__ out) {
    const int q = blockIdx.x * blockDim.x + threadIdx.x;  // quad index within one image
    if (q >= HW / 4) return;
    const int c = blockIdx.y;
    const int b = blockIdx.z;
    const int local = q * 4;

    const int4 i4 = *(const int4*)(widx + (size_t)b * HW + local);
    float4 o;
    o.x = (i4.x < 0) ? 0.0f : feat[(size_t)i4.x * Cc + c];
    o.y = (i4.y < 0) ? 0.0f : feat[(size_t)i4.y * Cc + c];
    o.z = (i4.z < 0) ? 0.0f : feat[(size_t)i4.z * Cc + c];
    o.w = (i4.w < 0) ? 0.0f : feat[(size_t)i4.w * Cc + c];

    *(float4*)(out + ((size_t)(b * Cc + c) * HW + local)) = o;
}

extern "C" void kernel_launch(void* const* d_in, const int* in_sizes, int n_in,
                              void* d_out, int out_size, void* d_ws, size_t ws_size,
                              hipStream_t stream) {
    const float* features = (const float*)d_in[0];
    const int*   coords   = (const int*)d_in[1];
    const float* Km       = (const float*)d_in[2];
    const int N = in_sizes[1] / 4;  // 200000

    unsigned long long* entries = (unsigned long long*)d_ws;
    int* widx = (int*)((char*)d_ws + (size_t)NUM_PIX * 8);

    float* out_feat = (float*)d_out;                          // B*C*H*W
    float* out_inv  = (float*)d_out + (size_t)Bc * Cc * HW;   // B*H*W

    // 0xFF-fill == every entry ~0ULL (empty). rocclr fill path, one fewer launch.
    hipMemsetAsync(entries, 0xFF, (size_t)NUM_PIX * 8, stream);

    scatter_points<<<(N + 255) / 256, 256, 0, stream>>>(coords, Km, entries, N);

    decode_entries<<<(NUM_PIX + 255) / 256, 256, 0, stream>>>(entries, widx, out_inv);

    dim3 ggrid((HW / 4 + 255) / 256, Cc, Bc);
    gather_features<<<ggrid, 256, 0, stream>>>(widx, features, out_feat);
}